// Round 4
// baseline (501.872 us; speedup 1.0000x reference)
//
#include <hip/hip_runtime.h>

typedef float f32x4 __attribute__((ext_vector_type(4)));
typedef short bf16x8 __attribute__((ext_vector_type(8)));

#define AS1 __attribute__((address_space(1)))
#define AS3 __attribute__((address_space(3)))

__device__ __forceinline__ void gl16(const void* g, void* l) {
  __builtin_amdgcn_global_load_lds((const AS1 unsigned int*)g,
                                   (AS3 unsigned int*)l, 16, 0, 0);
}

__device__ __forceinline__ unsigned short f2bf(float f) {
  unsigned u = __float_as_uint(f);
  u = u + 0x7FFFu + ((u >> 16) & 1u);   // RNE
  return (unsigned short)(u >> 16);
}

// ---------------- K1: style = s @ style_weight^T + style_bias  [N=4, Cin=64]
__global__ __launch_bounds__(256) void k_style(const float* __restrict__ s,
                                               const float* __restrict__ sw,
                                               const float* __restrict__ sb,
                                               float* __restrict__ style) {
  int t = threadIdx.x;
  int n = t >> 6, i = t & 63;
  float acc = sb[i];
  const float* sp = s + n * 512;
  const float* wp = sw + i * 512;
  for (int k = 0; k < 512; ++k) acc += sp[k] * wp[k];
  style[t] = acc;  // t == n*64 + i
}

// ---------------- K2: modulate + demodulate -> bf16, layout wm[(n*27+k)*64+o][i]
// row = 128B, chunk(16B) XOR-swizzled by (o&7).
__global__ __launch_bounds__(256) void k_wmod(const float* __restrict__ weight,
                                              const float* __restrict__ style,
                                              unsigned short* __restrict__ wm) {
  int o = blockIdx.x, n = blockIdx.y, t = threadIdx.x;
  int lane = t & 63, wv = t >> 6;
  const float* wp = weight + o * 1728;   // [i][27]
  const float* st = style + n * 64;
  float v[7];
  float ss = 0.f;
#pragma unroll
  for (int j = 0; j < 7; ++j) {
    int idx = t + j * 256;
    float w = 0.f;
    if (idx < 1728) {
      int i = idx / 27;
      w = wp[idx] * st[i];
    }
    v[j] = w;
    ss += w * w;
  }
#pragma unroll
  for (int off = 32; off > 0; off >>= 1) ss += __shfl_down(ss, off);
  __shared__ float red[4];
  if (lane == 0) red[wv] = ss;
  __syncthreads();
  float total = red[0] + red[1] + red[2] + red[3];
  float dm = 1.0f / sqrtf(total + 1e-8f);
#pragma unroll
  for (int j = 0; j < 7; ++j) {
    int idx = t + j * 256;
    if (idx < 1728) {
      int i = idx / 27, k = idx - i * 27;
      int g = (n * 27 + k) * 64 + o;
      wm[g * 64 + (((i >> 3) ^ (o & 7)) << 3) + (i & 7)] = f2bf(v[j] * dm);
    }
  }
}

// ---------------- K3: x[N][64][48^3] fp32 -> xT[(n*110592+p)][i] bf16,
// 16B chunks XOR-swizzled by (p&7). 128p x 64i tile per block via LDS.
__global__ __launch_bounds__(256) void k_xpose(const float* __restrict__ x,
                                               unsigned short* __restrict__ xT) {
  __shared__ unsigned tile[128][33];
  int n = blockIdx.y;
  int p0 = blockIdx.x * 128;
  int t = threadIdx.x;
  int wv = t >> 6, lane = t & 63;
  const float* xb = x + (size_t)n * 64 * 110592 + p0;
#pragma unroll
  for (int c = 0; c < 8; ++c) {
    int i2 = c * 4 + wv;      // pair index 0..31
    int i = i2 * 2;
    int pl = lane * 2;
    const float* r0 = xb + (size_t)i * 110592 + pl;
    const float* r1 = r0 + 110592;
    float2 a = *(const float2*)r0;
    float2 b = *(const float2*)r1;
    tile[pl][i2]     = (unsigned)f2bf(a.x) | ((unsigned)f2bf(b.x) << 16);
    tile[pl + 1][i2] = (unsigned)f2bf(a.y) | ((unsigned)f2bf(b.y) << 16);
  }
  __syncthreads();
  uint4* dst = (uint4*)xT;
#pragma unroll
  for (int c = 0; c < 4; ++c) {
    int pl = (t >> 3) + c * 32;
    int r = t & 7;  // chunk index (8 i's)
    uint4 u;
    u.x = tile[pl][r * 4 + 0];
    u.y = tile[pl][r * 4 + 1];
    u.z = tile[pl][r * 4 + 2];
    u.w = tile[pl][r * 4 + 3];
    int R = n * 110592 + p0 + pl;
    dst[(size_t)R * 8 + (r ^ (pl & 7))] = u;   // p0 % 8 == 0 -> key = pl&7
  }
}

// ---------------- K4: implicit-GEMM conv. Block: n, 192 flat positions, o=64.
// 4 waves, wave tile 64o x 48p. B slab (296 rows, 37KB) in LDS once per kd;
// A in registers from global (L1-hot), pipelined one tap ahead.
// 37KB LDS + ~95 VGPR -> 4 blocks/CU = 16 waves = 4/SIMD.
__global__ __launch_bounds__(256, 4) void k_conv(const unsigned short* __restrict__ xT,
                                                 const unsigned short* __restrict__ wm,
                                                 const float* __restrict__ bias,
                                                 float* __restrict__ out) {
  __shared__ uint4 Bl4[(296 * 128) / 16];   // 296 rows x 128B = 37888B
  char* Bl = (char*)Bl4;
  int n = blockIdx.y;
  int p0 = blockIdx.x * 192;
  int t = threadIdx.x;
  int lane = t & 63, wv = t >> 6;   // wv in 0..3
  int l15 = lane & 15, lhi = lane >> 4;
  f32x4 acc[4][3] = {};

  const char* xb = (const char*)xT + ((size_t)(n * 110592 + p0)) * 128;
  const char* wb = (const char*)wm + (size_t)n * 27 * 8192;

  // per-lane A fragment byte offsets within one 8KB tap tile
  int aoff[8];
#pragma unroll
  for (int m = 0; m < 4; ++m)
#pragma unroll
    for (int ih = 0; ih < 2; ++ih) {
      int orow = m * 16 + l15;
      int c = lhi + ih * 4;
      aoff[m * 2 + ih] = orow * 128 + ((c ^ (orow & 7)) << 4);
    }

  bf16x8 a[2][8];
  // prologue: load tap 0 A fragments
#pragma unroll
  for (int j = 0; j < 8; ++j) a[0][j] = *(const bf16x8*)(wb + aoff[j]);

#pragma unroll
  for (int kd = 0; kd < 3; ++kd) {
    __syncthreads();  // all waves done reading Bl of previous kd
    const char* src = xb + (size_t)kd * (2304 * 128);
    for (int cc = wv; cc < 37; cc += 4)   // 37 chunks = 296 rows
      gl16(src + cc * 1024 + lane * 16, Bl + cc * 1024);
    __syncthreads();  // drains staging -> B slab ready
#pragma unroll
    for (int tap = 0; tap < 9; ++tap) {
      const int sidx = kd * 9 + tap;
      const int cur = sidx & 1;
      const int nxt_sidx = sidx + 1;
      if (nxt_sidx < 27) {
        const char* ap = wb + (size_t)nxt_sidx * 8192;
#pragma unroll
        for (int j = 0; j < 8; ++j)
          a[nxt_sidx & 1][j] = *(const bf16x8*)(ap + aoff[j]);
      }
      const int kh = tap / 3, kw = tap % 3;
      const int rbase = wv * 48 + kh * 48 + kw;
#pragma unroll
      for (int ih = 0; ih < 2; ++ih) {
        int c = lhi + ih * 4;
        bf16x8 b[3];
#pragma unroll
        for (int q = 0; q < 3; ++q) {
          int r = rbase + q * 16 + l15;
          b[q] = *(const bf16x8*)(Bl + r * 128 + ((c ^ (r & 7)) << 4));
        }
        __builtin_amdgcn_s_setprio(1);
#pragma unroll
        for (int m = 0; m < 4; ++m)
#pragma unroll
          for (int q = 0; q < 3; ++q)
            acc[m][q] = __builtin_amdgcn_mfma_f32_16x16x32_bf16(a[cur][m * 2 + ih], b[q], acc[m][q], 0, 0, 0);
        __builtin_amdgcn_s_setprio(0);
      }
    }
  }

  float bv[4][4];
#pragma unroll
  for (int m = 0; m < 4; ++m)
#pragma unroll
    for (int r = 0; r < 4; ++r) bv[m][r] = bias[m * 16 + lhi * 4 + r];

  float* ob = out + (size_t)n * 64 * 97336;
#pragma unroll
  for (int q = 0; q < 3; ++q) {
    int p = p0 + wv * 48 + q * 16 + l15;
    int d = p / 2304;
    int rem = p - d * 2304;
    int h = rem / 48;
    int w = rem - h * 48;
    if (h < 46 && w < 46) {  // d < 46 guaranteed: p <= 105983 (552*192 = 105984)
      int base = d * 2116 + h * 46 + w;
#pragma unroll
      for (int m = 0; m < 4; ++m)
#pragma unroll
        for (int r = 0; r < 4; ++r) {
          int o = m * 16 + lhi * 4 + r;
          ob[(size_t)o * 97336 + base] = acc[m][q][r] + bv[m][r];
        }
    }
  }
}

extern "C" void kernel_launch(void* const* d_in, const int* in_sizes, int n_in,
                              void* d_out, int out_size, void* d_ws, size_t ws_size,
                              hipStream_t stream) {
  const float* x    = (const float*)d_in[0];
  const float* s    = (const float*)d_in[1];
  const float* sw   = (const float*)d_in[2];
  const float* sb   = (const float*)d_in[3];
  const float* wt   = (const float*)d_in[4];
  const float* bias = (const float*)d_in[5];
  float* out = (float*)d_out;

  // ws layout: [0,1024) style fp32; [1024, 885760) wm bf16 (4*27*64*64);
  // [885760, +57,225,472) xT bf16 incl. tail pad for shift overreach.
  float* style          = (float*)d_ws;
  unsigned short* wm    = (unsigned short*)((char*)d_ws + 1024);
  unsigned short* xT    = (unsigned short*)((char*)d_ws + 1024 + 884736);

  hipLaunchKernelGGL(k_style, dim3(1), dim3(256), 0, stream, s, sw, sb, style);
  hipLaunchKernelGGL(k_wmod, dim3(64, 4), dim3(256), 0, stream, wt, style, wm);
  hipLaunchKernelGGL(k_xpose, dim3(864, 4), dim3(256), 0, stream, x, xT);
  hipLaunchKernelGGL(k_conv, dim3(552, 4), dim3(256), 0, stream, xT, wm, bias, out);
}

// Round 5
// 154.812 us; speedup vs baseline: 3.2418x; 3.2418x over previous
//
#include <hip/hip_runtime.h>

typedef float f32x4 __attribute__((ext_vector_type(4)));
typedef short bf16x8 __attribute__((ext_vector_type(8)));

#define AS1 __attribute__((address_space(1)))
#define AS3 __attribute__((address_space(3)))

__device__ __forceinline__ void gl16(const void* g, void* l) {
  __builtin_amdgcn_global_load_lds((const AS1 unsigned int*)g,
                                   (AS3 unsigned int*)l, 16, 0, 0);
}

__device__ __forceinline__ unsigned short f2bf(float f) {
  unsigned u = __float_as_uint(f);
  u = u + 0x7FFFu + ((u >> 16) & 1u);   // RNE
  return (unsigned short)(u >> 16);
}

// ---------------- K1: style = s @ style_weight^T + style_bias  [N=4, Cin=64]
__global__ __launch_bounds__(256) void k_style(const float* __restrict__ s,
                                               const float* __restrict__ sw,
                                               const float* __restrict__ sb,
                                               float* __restrict__ style) {
  int t = threadIdx.x;
  int n = t >> 6, i = t & 63;
  float acc = sb[i];
  const float* sp = s + n * 512;
  const float* wp = sw + i * 512;
  for (int k = 0; k < 512; ++k) acc += sp[k] * wp[k];
  style[t] = acc;  // t == n*64 + i
}

// ---------------- K2: modulate + demodulate -> bf16, layout wm[(n*27+k)*64+o][i]
// row = 128B, chunk(16B) XOR-swizzled by (o&7).
__global__ __launch_bounds__(256) void k_wmod(const float* __restrict__ weight,
                                              const float* __restrict__ style,
                                              unsigned short* __restrict__ wm) {
  int o = blockIdx.x, n = blockIdx.y, t = threadIdx.x;
  int lane = t & 63, wv = t >> 6;
  const float* wp = weight + o * 1728;   // [i][27]
  const float* st = style + n * 64;
  float v[7];
  float ss = 0.f;
#pragma unroll
  for (int j = 0; j < 7; ++j) {
    int idx = t + j * 256;
    float w = 0.f;
    if (idx < 1728) {
      int i = idx / 27;
      w = wp[idx] * st[i];
    }
    v[j] = w;
    ss += w * w;
  }
#pragma unroll
  for (int off = 32; off > 0; off >>= 1) ss += __shfl_down(ss, off);
  __shared__ float red[4];
  if (lane == 0) red[wv] = ss;
  __syncthreads();
  float total = red[0] + red[1] + red[2] + red[3];
  float dm = 1.0f / sqrtf(total + 1e-8f);
#pragma unroll
  for (int j = 0; j < 7; ++j) {
    int idx = t + j * 256;
    if (idx < 1728) {
      int i = idx / 27, k = idx - i * 27;
      int g = (n * 27 + k) * 64 + o;
      wm[g * 64 + (((i >> 3) ^ (o & 7)) << 3) + (i & 7)] = f2bf(v[j] * dm);
    }
  }
}

// ---------------- K3: x[N][64][48^3] fp32 -> xT[(n*110592+p)][i] bf16,
// 16B chunks XOR-swizzled by (p&7). 128p x 64i tile per block via LDS.
__global__ __launch_bounds__(256) void k_xpose(const float* __restrict__ x,
                                               unsigned short* __restrict__ xT) {
  __shared__ unsigned tile[128][33];
  int n = blockIdx.y;
  int p0 = blockIdx.x * 128;
  int t = threadIdx.x;
  int wv = t >> 6, lane = t & 63;
  const float* xb = x + (size_t)n * 64 * 110592 + p0;
#pragma unroll
  for (int c = 0; c < 8; ++c) {
    int i2 = c * 4 + wv;      // pair index 0..31
    int i = i2 * 2;
    int pl = lane * 2;
    const float* r0 = xb + (size_t)i * 110592 + pl;
    const float* r1 = r0 + 110592;
    float2 a = *(const float2*)r0;
    float2 b = *(const float2*)r1;
    tile[pl][i2]     = (unsigned)f2bf(a.x) | ((unsigned)f2bf(b.x) << 16);
    tile[pl + 1][i2] = (unsigned)f2bf(a.y) | ((unsigned)f2bf(b.y) << 16);
  }
  __syncthreads();
  uint4* dst = (uint4*)xT;
#pragma unroll
  for (int c = 0; c < 4; ++c) {
    int pl = (t >> 3) + c * 32;
    int r = t & 7;  // chunk index (8 i's)
    uint4 u;
    u.x = tile[pl][r * 4 + 0];
    u.y = tile[pl][r * 4 + 1];
    u.z = tile[pl][r * 4 + 2];
    u.w = tile[pl][r * 4 + 3];
    int R = n * 110592 + p0 + pl;
    dst[(size_t)R * 8 + (r ^ (pl & 7))] = u;   // p0 % 8 == 0 -> key = pl&7
  }
}

// ---------------- K4: implicit-GEMM conv. 256p x 64o per block, 4 waves,
// wave tile 64o x 64p. B slab (46KB) staged per kd; A double-buffered in LDS
// (2x8KB) staged ONE TAP AHEAD via global_load_lds. Per-tap raw barriers with
// counted-cheap vmcnt(0) (own 2 gl16s, issued ~600cy earlier). XCD-chunked
// block swizzle (1656 = 8*207). VGPR target: R1's proven ~108.
__global__ __launch_bounds__(256) void k_conv(const unsigned short* __restrict__ xT,
                                              const unsigned short* __restrict__ wm,
                                              const float* __restrict__ bias,
                                              float* __restrict__ out) {
  __shared__ uint4 Bl4[46080 / 16];     // 360 rows x 128B
  __shared__ uint4 Al4[2][8192 / 16];   // A dbuf: 64 rows x 128B each
  char* Bl = (char*)Bl4;

  int bid = blockIdx.x;                       // 0..1655 dispatch slot
  int orig = (bid & 7) * 207 + (bid >> 3);    // chunked XCD swizzle (bijective)
  int n = orig / 414;
  int pb = orig - n * 414;
  int p0 = pb * 256;

  int t = threadIdx.x;
  int lane = t & 63, wv = t >> 6;
  int l15 = lane & 15, lhi = lane >> 4;
  f32x4 acc[4][4] = {};

  const char* xb = (const char*)xT + ((size_t)(n * 110592 + p0)) * 128;
  const char* wb = (const char*)wm + (size_t)n * 27 * 8192;

  // prologue: issue A-stage for tap 0 into Al[0]
  {
    const char* ap = wb;
    gl16(ap + wv * 1024 + lane * 16, (char*)Al4[0] + wv * 1024);
    gl16(ap + (wv + 4) * 1024 + lane * 16, (char*)Al4[0] + (wv + 4) * 1024);
  }

#pragma unroll
  for (int kd = 0; kd < 3; ++kd) {
    // stage B slab for this kd (previous kd's reads completed before the
    // trailing barrier of its last tap)
    const char* src = xb + (size_t)kd * (2304 * 128);
    for (int cc = wv; cc < 45; cc += 4)
      gl16(src + cc * 1024 + lane * 16, Bl + cc * 1024);
    asm volatile("s_waitcnt vmcnt(0)" ::: "memory");  // B slab + pending A retired
    __builtin_amdgcn_s_barrier();
    __builtin_amdgcn_sched_barrier(0);

#pragma unroll
    for (int tap = 0; tap < 9; ++tap) {
      const int s = kd * 9 + tap;     // global tap 0..26
      const int cur = s & 1;
      // issue A-stage for tap s+1 into Al[!cur] (safe: its readers finished
      // before the barrier we just crossed)
      if (s + 1 < 27) {
        const char* ap = wb + (size_t)(s + 1) * 8192;
        gl16(ap + wv * 1024 + lane * 16, (char*)Al4[cur ^ 1] + wv * 1024);
        gl16(ap + (wv + 4) * 1024 + lane * 16, (char*)Al4[cur ^ 1] + (wv + 4) * 1024);
      }
      const int kh = tap / 3, kw = tap - kh * 3;
      const int rbase = wv * 64 + kh * 48 + kw;
      const char* Alc = (const char*)Al4[cur];
#pragma unroll
      for (int ih = 0; ih < 2; ++ih) {
        int c = lhi + ih * 4;
        bf16x8 a[4], b[4];
#pragma unroll
        for (int m = 0; m < 4; ++m) {
          int orow = m * 16 + l15;
          a[m] = *(const bf16x8*)(Alc + orow * 128 + ((c ^ (orow & 7)) << 4));
        }
#pragma unroll
        for (int q = 0; q < 4; ++q) {
          int r = rbase + q * 16 + l15;
          b[q] = *(const bf16x8*)(Bl + r * 128 + ((c ^ (r & 7)) << 4));
        }
        __builtin_amdgcn_s_setprio(1);
#pragma unroll
        for (int m = 0; m < 4; ++m)
#pragma unroll
          for (int q = 0; q < 4; ++q)
            acc[m][q] = __builtin_amdgcn_mfma_f32_16x16x32_bf16(a[m], b[q], acc[m][q], 0, 0, 0);
        __builtin_amdgcn_s_setprio(0);
      }
      // own 2 gl16s (issued at tap start, ~600cy ago) retired -> after the
      // barrier, Al[!cur] is complete for everyone
      asm volatile("s_waitcnt vmcnt(0)" ::: "memory");
      __builtin_amdgcn_s_barrier();
      __builtin_amdgcn_sched_barrier(0);
    }
  }

  float bv[4][4];
#pragma unroll
  for (int m = 0; m < 4; ++m)
#pragma unroll
    for (int r = 0; r < 4; ++r) bv[m][r] = bias[m * 16 + lhi * 4 + r];

  float* ob = out + (size_t)n * 64 * 97336;
#pragma unroll
  for (int q = 0; q < 4; ++q) {
    int p = p0 + wv * 64 + q * 16 + l15;
    int d = p / 2304;
    int rem = p - d * 2304;
    int h = rem / 48;
    int w = rem - h * 48;
    if (h < 46 && w < 46) {  // d < 46 guaranteed: p <= 105983
      int base = d * 2116 + h * 46 + w;
#pragma unroll
      for (int m = 0; m < 4; ++m)
#pragma unroll
        for (int r = 0; r < 4; ++r) {
          int o = m * 16 + lhi * 4 + r;
          ob[(size_t)o * 97336 + base] = acc[m][q][r] + bv[m][r];
        }
    }
  }
}

extern "C" void kernel_launch(void* const* d_in, const int* in_sizes, int n_in,
                              void* d_out, int out_size, void* d_ws, size_t ws_size,
                              hipStream_t stream) {
  const float* x    = (const float*)d_in[0];
  const float* s    = (const float*)d_in[1];
  const float* sw   = (const float*)d_in[2];
  const float* sb   = (const float*)d_in[3];
  const float* wt   = (const float*)d_in[4];
  const float* bias = (const float*)d_in[5];
  float* out = (float*)d_out;

  // ws layout: [0,1024) style fp32; [1024, 885760) wm bf16 (4*27*64*64);
  // [885760, +57,225,472) xT bf16 incl. tail pad for shift overreach.
  float* style          = (float*)d_ws;
  unsigned short* wm    = (unsigned short*)((char*)d_ws + 1024);
  unsigned short* xT    = (unsigned short*)((char*)d_ws + 1024 + 884736);

  hipLaunchKernelGGL(k_style, dim3(1), dim3(256), 0, stream, s, sw, sb, style);
  hipLaunchKernelGGL(k_wmod, dim3(64, 4), dim3(256), 0, stream, wt, style, wm);
  hipLaunchKernelGGL(k_xpose, dim3(864, 4), dim3(256), 0, stream, x, xT);
  hipLaunchKernelGGL(k_conv, dim3(1656), dim3(256), 0, stream, xT, wm, bias, out);
}

// Round 6
// 150.785 us; speedup vs baseline: 3.3284x; 1.0267x over previous
//
#include <hip/hip_runtime.h>

typedef float f32x4 __attribute__((ext_vector_type(4)));
typedef short bf16x8 __attribute__((ext_vector_type(8)));

#define AS1 __attribute__((address_space(1)))
#define AS3 __attribute__((address_space(3)))

__device__ __forceinline__ void gl16(const void* g, void* l) {
  __builtin_amdgcn_global_load_lds((const AS1 unsigned int*)g,
                                   (AS3 unsigned int*)l, 16, 0, 0);
}

__device__ __forceinline__ unsigned short f2bf(float f) {
  unsigned u = __float_as_uint(f);
  u = u + 0x7FFFu + ((u >> 16) & 1u);   // RNE
  return (unsigned short)(u >> 16);
}

// ---------------- K1: style = s @ style_weight^T + style_bias  [N=4, Cin=64]
__global__ __launch_bounds__(256) void k_style(const float* __restrict__ s,
                                               const float* __restrict__ sw,
                                               const float* __restrict__ sb,
                                               float* __restrict__ style) {
  int t = threadIdx.x;
  int n = t >> 6, i = t & 63;
  float acc = sb[i];
  const float* sp = s + n * 512;
  const float* wp = sw + i * 512;
  for (int k = 0; k < 512; ++k) acc += sp[k] * wp[k];
  style[t] = acc;  // t == n*64 + i
}

// ---------------- K2: modulate + demodulate -> bf16, layout wm[(n*27+k)*64+o][i]
// row = 128B, chunk(16B) XOR-swizzled by (o&7).
__global__ __launch_bounds__(256) void k_wmod(const float* __restrict__ weight,
                                              const float* __restrict__ style,
                                              unsigned short* __restrict__ wm) {
  int o = blockIdx.x, n = blockIdx.y, t = threadIdx.x;
  int lane = t & 63, wv = t >> 6;
  const float* wp = weight + o * 1728;   // [i][27]
  const float* st = style + n * 64;
  float v[7];
  float ss = 0.f;
#pragma unroll
  for (int j = 0; j < 7; ++j) {
    int idx = t + j * 256;
    float w = 0.f;
    if (idx < 1728) {
      int i = idx / 27;
      w = wp[idx] * st[i];
    }
    v[j] = w;
    ss += w * w;
  }
#pragma unroll
  for (int off = 32; off > 0; off >>= 1) ss += __shfl_down(ss, off);
  __shared__ float red[4];
  if (lane == 0) red[wv] = ss;
  __syncthreads();
  float total = red[0] + red[1] + red[2] + red[3];
  float dm = 1.0f / sqrtf(total + 1e-8f);
#pragma unroll
  for (int j = 0; j < 7; ++j) {
    int idx = t + j * 256;
    if (idx < 1728) {
      int i = idx / 27, k = idx - i * 27;
      int g = (n * 27 + k) * 64 + o;
      wm[g * 64 + (((i >> 3) ^ (o & 7)) << 3) + (i & 7)] = f2bf(v[j] * dm);
    }
  }
}

// ---------------- K3: x[N][64][48^3] fp32 -> xT[(n*110592+p)][i] bf16,
// 16B chunks XOR-swizzled by (p&7). 128p x 64i tile per block via LDS.
__global__ __launch_bounds__(256) void k_xpose(const float* __restrict__ x,
                                               unsigned short* __restrict__ xT) {
  __shared__ unsigned tile[128][33];
  int n = blockIdx.y;
  int p0 = blockIdx.x * 128;
  int t = threadIdx.x;
  int wv = t >> 6, lane = t & 63;
  const float* xb = x + (size_t)n * 64 * 110592 + p0;
#pragma unroll
  for (int c = 0; c < 8; ++c) {
    int i2 = c * 4 + wv;      // pair index 0..31
    int i = i2 * 2;
    int pl = lane * 2;
    const float* r0 = xb + (size_t)i * 110592 + pl;
    const float* r1 = r0 + 110592;
    float2 a = *(const float2*)r0;
    float2 b = *(const float2*)r1;
    tile[pl][i2]     = (unsigned)f2bf(a.x) | ((unsigned)f2bf(b.x) << 16);
    tile[pl + 1][i2] = (unsigned)f2bf(a.y) | ((unsigned)f2bf(b.y) << 16);
  }
  __syncthreads();
  uint4* dst = (uint4*)xT;
#pragma unroll
  for (int c = 0; c < 4; ++c) {
    int pl = (t >> 3) + c * 32;
    int r = t & 7;  // chunk index (8 i's)
    uint4 u;
    u.x = tile[pl][r * 4 + 0];
    u.y = tile[pl][r * 4 + 1];
    u.z = tile[pl][r * 4 + 2];
    u.w = tile[pl][r * 4 + 3];
    int R = n * 110592 + p0 + pl;
    dst[(size_t)R * 8 + (r ^ (pl & 7))] = u;   // p0 % 8 == 0 -> key = pl&7
  }
}

// ---------------- K4: implicit-GEMM conv. 256p x 64o per block, 4 waves,
// wave tile 64o x 64p. B slab (46KB) = ONLY LDS -> 3 blocks/CU = 12 waves.
// A in REGISTERS, global-loaded (L1-hot, all waves share the 8KB tap tile),
// double-buffered one tap ahead; sched_barrier(0) pins prefetch issue so the
// first MFMA gets a counted vmcnt(8), never a drain. Inner loop barrier-free.
// XCD-chunked block swizzle (1656 = 8*207).
__global__ __launch_bounds__(256) void k_conv(const unsigned short* __restrict__ xT,
                                              const unsigned short* __restrict__ wm,
                                              const float* __restrict__ bias,
                                              float* __restrict__ out) {
  __shared__ uint4 Bl4[46080 / 16];     // 360 rows x 128B
  char* Bl = (char*)Bl4;

  int bid = blockIdx.x;                       // 0..1655 dispatch slot
  int orig = (bid & 7) * 207 + (bid >> 3);    // chunked XCD swizzle (bijective)
  int n = orig / 414;
  int pb = orig - n * 414;
  int p0 = pb * 256;

  int t = threadIdx.x;
  int lane = t & 63, wv = t >> 6;
  int l15 = lane & 15, lhi = lane >> 4;
  f32x4 acc[4][4] = {};

  const char* xb = (const char*)xT + ((size_t)(n * 110592 + p0)) * 128;
  const char* wb = (const char*)wm + (size_t)n * 27 * 8192;

  // per-lane A fragment byte offsets within one 8KB tap tile (swizzle baked
  // into wm layout by k_wmod)
  int aoff[8];
#pragma unroll
  for (int m = 0; m < 4; ++m)
#pragma unroll
    for (int ih = 0; ih < 2; ++ih) {
      int orow = m * 16 + l15;
      int c = lhi + ih * 4;
      aoff[m * 2 + ih] = orow * 128 + ((c ^ (orow & 7)) << 4);
    }

  bf16x8 aA[8], aB[8];
  // prologue: tap 0 A fragments into aA
#pragma unroll
  for (int j = 0; j < 8; ++j) aA[j] = *(const bf16x8*)(wb + aoff[j]);

  // One tap: prefetch NXT <- tap (S+1), pin issue, then B-reads + MFMA on CUR.
#define TAP(CUR, NXT, S, TP)                                                   \
  do {                                                                         \
    if ((S) + 1 < 27) {                                                        \
      const char* ap_ = wb + (size_t)((S) + 1) * 8192;                         \
      _Pragma("unroll") for (int j = 0; j < 8; ++j)                            \
          NXT[j] = *(const bf16x8*)(ap_ + aoff[j]);                            \
    }                                                                          \
    __builtin_amdgcn_sched_barrier(0);                                         \
    const int kh_ = (TP) / 3, kw_ = (TP) % 3;                                  \
    const int rbase_ = wv * 64 + kh_ * 48 + kw_;                               \
    _Pragma("unroll") for (int ih = 0; ih < 2; ++ih) {                         \
      int c_ = lhi + ih * 4;                                                   \
      bf16x8 b_[4];                                                            \
      _Pragma("unroll") for (int q = 0; q < 4; ++q) {                          \
        int r_ = rbase_ + q * 16 + l15;                                        \
        b_[q] = *(const bf16x8*)(Bl + r_ * 128 + ((c_ ^ (r_ & 7)) << 4));      \
      }                                                                        \
      __builtin_amdgcn_s_setprio(1);                                           \
      _Pragma("unroll") for (int m = 0; m < 4; ++m)                            \
          _Pragma("unroll") for (int q = 0; q < 4; ++q)                        \
              acc[m][q] = __builtin_amdgcn_mfma_f32_16x16x32_bf16(             \
                  CUR[m * 2 + ih], b_[q], acc[m][q], 0, 0, 0);                 \
      __builtin_amdgcn_s_setprio(0);                                           \
    }                                                                          \
  } while (0)

#pragma unroll
  for (int kd = 0; kd < 3; ++kd) {
    if (kd) __builtin_amdgcn_s_barrier();  // all waves done reading Bl
    const char* src = xb + (size_t)kd * (2304 * 128);
    for (int cc = wv; cc < 45; cc += 4)
      gl16(src + cc * 1024 + lane * 16, Bl + cc * 1024);
    asm volatile("s_waitcnt vmcnt(0)" ::: "memory");  // B slab complete
    __builtin_amdgcn_s_barrier();
    __builtin_amdgcn_sched_barrier(0);
#pragma unroll
    for (int tp = 0; tp < 9; ++tp) {
      const int s = kd * 9 + tp;
      if ((s & 1) == 0) TAP(aA, aB, s, tp);
      else              TAP(aB, aA, s, tp);
    }
  }
#undef TAP

  float bv[4][4];
#pragma unroll
  for (int m = 0; m < 4; ++m)
#pragma unroll
    for (int r = 0; r < 4; ++r) bv[m][r] = bias[m * 16 + lhi * 4 + r];

  float* ob = out + (size_t)n * 64 * 97336;
#pragma unroll
  for (int q = 0; q < 4; ++q) {
    int p = p0 + wv * 64 + q * 16 + l15;
    int d = p / 2304;
    int rem = p - d * 2304;
    int h = rem / 48;
    int w = rem - h * 48;
    if (h < 46 && w < 46) {  // d < 46 guaranteed: p <= 105983
      int base = d * 2116 + h * 46 + w;
#pragma unroll
      for (int m = 0; m < 4; ++m)
#pragma unroll
        for (int r = 0; r < 4; ++r) {
          int o = m * 16 + lhi * 4 + r;
          ob[(size_t)o * 97336 + base] = acc[m][q][r] + bv[m][r];
        }
    }
  }
}

extern "C" void kernel_launch(void* const* d_in, const int* in_sizes, int n_in,
                              void* d_out, int out_size, void* d_ws, size_t ws_size,
                              hipStream_t stream) {
  const float* x    = (const float*)d_in[0];
  const float* s    = (const float*)d_in[1];
  const float* sw   = (const float*)d_in[2];
  const float* sb   = (const float*)d_in[3];
  const float* wt   = (const float*)d_in[4];
  const float* bias = (const float*)d_in[5];
  float* out = (float*)d_out;

  // ws layout: [0,1024) style fp32; [1024, 885760) wm bf16 (4*27*64*64);
  // [885760, +57,225,472) xT bf16 incl. tail pad for shift overreach.
  float* style          = (float*)d_ws;
  unsigned short* wm    = (unsigned short*)((char*)d_ws + 1024);
  unsigned short* xT    = (unsigned short*)((char*)d_ws + 1024 + 884736);

  hipLaunchKernelGGL(k_style, dim3(1), dim3(256), 0, stream, s, sw, sb, style);
  hipLaunchKernelGGL(k_wmod, dim3(64, 4), dim3(256), 0, stream, wt, style, wm);
  hipLaunchKernelGGL(k_xpose, dim3(864, 4), dim3(256), 0, stream, x, xT);
  hipLaunchKernelGGL(k_conv, dim3(1656), dim3(256), 0, stream, xT, wm, bias, out);
}